// Round 4
// baseline (10621.909 us; speedup 1.0000x reference)
//
#include <hip/hip_runtime.h>

typedef unsigned short u16;
typedef unsigned int   u32;

typedef __attribute__((ext_vector_type(8)))  short bf16x8;
typedef __attribute__((ext_vector_type(4)))  float f32x4;
typedef __attribute__((ext_vector_type(4)))  u32   u32x4;
typedef __attribute__((ext_vector_type(16))) float f32x16;

#define B_  32
#define S_  1024
#define NH_ 512
#define G4_ 2048   // 4*NH
#define SC_NWG 8   // scan workgroups (8 waves each = 64 waves total)

__device__ __forceinline__ float bf2f(u16 h) {
    return __uint_as_float(((u32)h) << 16);
}
__device__ __forceinline__ u16 f2bf(float f) {
    u32 u = __float_as_uint(f);
    return (u16)((u + 0x7fffu + ((u >> 16) & 1u)) >> 16);
}
__device__ __forceinline__ float fsig(float x) {
    return 1.0f / (1.0f + __expf(-x));
}
__device__ __forceinline__ float ftanh(float x) {
    return 1.0f - 2.0f / (__expf(2.0f * x) + 1.0f);
}

// ---------------- fp32 -> bf16 elementwise convert (vectorized x4) ----------
__global__ void cvt_bf16_kernel(const float* __restrict__ in, u16* __restrict__ out, int n4) {
    int i = blockIdx.x * blockDim.x + threadIdx.x;
    if (i >= n4) return;
    f32x4 v = ((const f32x4*)in)[i];
    unsigned long long pk =
        (unsigned long long)f2bf(v[0]) |
        ((unsigned long long)f2bf(v[1]) << 16) |
        ((unsigned long long)f2bf(v[2]) << 32) |
        ((unsigned long long)f2bf(v[3]) << 48);
    ((unsigned long long*)out)[i] = pk;
}

// ---------------- fp32 [R][C] -> bf16 [C][R] transpose-convert --------------
__global__ void transpose_cvt_kernel(const float* __restrict__ in, u16* __restrict__ out,
                                     int R, int C) {
    __shared__ float tile[32][33];
    int bx = blockIdx.x, by = blockIdx.y;
    int tx = threadIdx.x & 31, ty = threadIdx.x >> 5;
    #pragma unroll
    for (int i = 0; i < 4; i++) {
        int r = by * 32 + ty + i * 8;
        tile[ty + i * 8][tx] = in[(size_t)r * C + bx * 32 + tx];
    }
    __syncthreads();
    #pragma unroll
    for (int i = 0; i < 4; i++) {
        int c = bx * 32 + ty + i * 8;
        out[(size_t)c * R + by * 32 + tx] = f2bf(tile[tx][ty + i * 8]);
    }
}

// ---------------- generic bf16 MFMA GEMM: C = A @ BT^T + bias ---------------
// A [M][K] bf16 row-major, BT [N][K] bf16, bias [N] f32.
// out_mode: 0 -> f32 row-major; 1 -> bf16 in SCAN ORDER [t][wg64][lane][r]
__global__ __launch_bounds__(256) void gemm_bf16_kernel(
    const u16* __restrict__ A, const u16* __restrict__ BT,
    const float* __restrict__ bias, void* __restrict__ Cp,
    int M, int N, int K, int out_mode)
{
    __shared__ u16 Al[128][40];
    __shared__ u16 Bl[128][40];
    int nbm = M >> 7;
    int bm = blockIdx.x % nbm, bn = blockIdx.x / nbm;
    int tid = threadIdx.x, lane = tid & 63, wave = tid >> 6;
    int wr = wave >> 1, wc = wave & 1;
    f32x4 acc[4][4];
    #pragma unroll
    for (int i = 0; i < 4; i++)
        #pragma unroll
        for (int j = 0; j < 4; j++)
            acc[i][j] = (f32x4){0.f, 0.f, 0.f, 0.f};
    int fr  = lane & 15;
    int kof = (lane >> 4) << 3;

    for (int k0 = 0; k0 < K; k0 += 32) {
        __syncthreads();
        #pragma unroll
        for (int i = 0; i < 2; i++) {
            int chunk = i * 256 + tid;
            int r = chunk >> 2, c = (chunk & 3) << 3;
            *(bf16x8*)&Al[r][c] = *(const bf16x8*)&A[(size_t)(bm * 128 + r) * K + k0 + c];
            *(bf16x8*)&Bl[r][c] = *(const bf16x8*)&BT[(size_t)(bn * 128 + r) * K + k0 + c];
        }
        __syncthreads();
        bf16x8 af[4], bfr[4];
        #pragma unroll
        for (int mi = 0; mi < 4; mi++)
            af[mi] = *(const bf16x8*)&Al[wr * 64 + mi * 16 + fr][kof];
        #pragma unroll
        for (int ni = 0; ni < 4; ni++)
            bfr[ni] = *(const bf16x8*)&Bl[wc * 64 + ni * 16 + fr][kof];
        #pragma unroll
        for (int mi = 0; mi < 4; mi++)
            #pragma unroll
            for (int ni = 0; ni < 4; ni++)
                acc[mi][ni] = __builtin_amdgcn_mfma_f32_16x16x32_bf16(af[mi], bfr[ni], acc[mi][ni], 0, 0, 0);
    }
    int rq = lane >> 4;
    #pragma unroll
    for (int mi = 0; mi < 4; mi++) {
        #pragma unroll
        for (int ni = 0; ni < 4; ni++) {
            int n = bn * 128 + wc * 64 + ni * 16 + fr;
            float bv = bias ? bias[n] : 0.f;
            #pragma unroll
            for (int r = 0; r < 4; r++) {
                int m = bm * 128 + wr * 64 + mi * 16 + rq * 4 + r;
                float v = acc[mi][ni][r] + bv;
                if (out_mode == 1) {
                    // scan-order store: [t][wg64][lane2][r2]
                    int t = m & 1023, b = m >> 10;
                    int g_loc = n >> 9, wg64i = (n >> 3) & 63, u_loc = n & 7;
                    int lane2 = (((b >> 2) & 1) << 5) | (u_loc << 2) | g_loc;
                    int r2 = (b & 3) | ((b >> 3) << 2);
                    ((u16*)Cp)[(((size_t)t * 64 + wg64i) * 64 + lane2) * 16 + r2] = f2bf(v);
                } else {
                    ((float*)Cp)[(size_t)m * N + n] = v;
                }
            }
        }
    }
}

// ---------------- LSTM scan: 8 persistent WGs x 8 waves ---------------------
// Self-validating exchange: h words are u32 (tag<<16 | bf16h) in hbuf[2][32][512].
// Producers fire-and-forget sc0sc1 stores; consumers poll their 128B slice
// until all 32 tags == t. Publication of tag t+1 implies the publisher staged
// all of h(t), so the double buffer can never be overwritten early, and a
// thread passing the poll for t+1 proves its own WG's waves finished step t
// (their tags are part of the poll) -- so one barrier per step suffices.
__global__ __launch_bounds__(512, 1) void lstm_scan_kernel(
    const u16* __restrict__ xw,    // [S][64][64][16] bf16 scan-order
    const u16* __restrict__ UT,    // [4H][NH] bf16
    u16* __restrict__ hseq,        // [B][S][NH] bf16
    u32* __restrict__ hbuf)        // [2][32][512] u32 tagged h
{
    __shared__ u16 h_lds[32][520];      // [batch][k], +8 u16 pad (0-conflict verified)
    __shared__ float gl[8][32][32];     // per-wave gate exchange

    const int tid  = threadIdx.x;
    const int wave = tid >> 6, lane = tid & 63;
    const int wg64 = (int)blockIdx.x * 8 + wave;
    const int col  = lane & 31, half = lane >> 5;
    const int u_loc = col >> 2, g_loc = col & 3;
    const int ucol  = g_loc * 512 + wg64 * 8 + u_loc;

    // persistent U B-fragments (128 regs/lane): zero weight traffic in loop
    bf16x8 ufrag[32];
    #pragma unroll
    for (int kk = 0; kk < 32; kk++)
        ufrag[kk] = *(const bf16x8*)&UT[(size_t)ucol * 512 + kk * 16 + half * 8];

    float cst[4] = {0.f, 0.f, 0.f, 0.f};

    // h(0) = 0 in LDS (t=0 skips the poll)
    {
        bf16x8 z = (bf16x8){0, 0, 0, 0, 0, 0, 0, 0};
        bf16x8* hf = (bf16x8*)&h_lds[0][0];
        for (int i = tid; i < 2080; i += 512) hf[i] = z;
    }

    const int sb_b = tid >> 4;          // batch row this thread stages
    const int sb_i = tid & 15;          // 128B (32 u32) chunk within the row
    u16* lds_dst = &h_lds[sb_b][sb_i * 32];

    for (int t = 0; t < 1024; t++) {
        // xw for this step: 32B contiguous per lane, issued early (HBM hidden)
        const u16* xp = xw + ((size_t)((size_t)t * 64 + wg64) * 64 + lane) * 16;
        bf16x8 xv0 = *(const bf16x8*)xp;
        bf16x8 xv1 = *(const bf16x8*)(xp + 8);

        if (t > 0) {
            const u32* src = hbuf + (((size_t)t & 1) << 14) + sb_b * 512 + sb_i * 32;
            const u32 tg = (u32)t;
            u32x4 v0, v1, v2, v3, v4, v5, v6, v7;
            while (1) {
                asm volatile(
                    "global_load_dwordx4 %0, %8, off sc0 sc1\n\t"
                    "global_load_dwordx4 %1, %8, off offset:16 sc0 sc1\n\t"
                    "global_load_dwordx4 %2, %8, off offset:32 sc0 sc1\n\t"
                    "global_load_dwordx4 %3, %8, off offset:48 sc0 sc1\n\t"
                    "global_load_dwordx4 %4, %8, off offset:64 sc0 sc1\n\t"
                    "global_load_dwordx4 %5, %8, off offset:80 sc0 sc1\n\t"
                    "global_load_dwordx4 %6, %8, off offset:96 sc0 sc1\n\t"
                    "global_load_dwordx4 %7, %8, off offset:112 sc0 sc1\n\t"
                    "s_waitcnt vmcnt(0)"
                    : "=&v"(v0), "=&v"(v1), "=&v"(v2), "=&v"(v3),
                      "=&v"(v4), "=&v"(v5), "=&v"(v6), "=&v"(v7)
                    : "v"(src) : "memory");
                u32 bad = 0;
                #pragma unroll
                for (int j = 0; j < 4; j++) {
                    bad |= (v0[j] >> 16) ^ tg; bad |= (v1[j] >> 16) ^ tg;
                    bad |= (v2[j] >> 16) ^ tg; bad |= (v3[j] >> 16) ^ tg;
                    bad |= (v4[j] >> 16) ^ tg; bad |= (v5[j] >> 16) ^ tg;
                    bad |= (v6[j] >> 16) ^ tg; bad |= (v7[j] >> 16) ^ tg;
                }
                if (!bad) break;
            }
            // pack tagged u32 pairs -> bf16 and write 64B to LDS
            u32x4 p0, p1, p2, p3;
            p0[0] = (v0[0] & 0xffffu) | (v0[1] << 16); p0[1] = (v0[2] & 0xffffu) | (v0[3] << 16);
            p0[2] = (v1[0] & 0xffffu) | (v1[1] << 16); p0[3] = (v1[2] & 0xffffu) | (v1[3] << 16);
            p1[0] = (v2[0] & 0xffffu) | (v2[1] << 16); p1[1] = (v2[2] & 0xffffu) | (v2[3] << 16);
            p1[2] = (v3[0] & 0xffffu) | (v3[1] << 16); p1[3] = (v3[2] & 0xffffu) | (v3[3] << 16);
            p2[0] = (v4[0] & 0xffffu) | (v4[1] << 16); p2[1] = (v4[2] & 0xffffu) | (v4[3] << 16);
            p2[2] = (v5[0] & 0xffffu) | (v5[1] << 16); p2[3] = (v5[2] & 0xffffu) | (v5[3] << 16);
            p3[0] = (v6[0] & 0xffffu) | (v6[1] << 16); p3[1] = (v6[2] & 0xffffu) | (v6[3] << 16);
            p3[2] = (v7[0] & 0xffffu) | (v7[1] << 16); p3[3] = (v7[2] & 0xffffu) | (v7[3] << 16);
            *(u32x4*)(lds_dst)      = p0;
            *(u32x4*)(lds_dst + 8)  = p1;
            *(u32x4*)(lds_dst + 16) = p2;
            *(u32x4*)(lds_dst + 24) = p3;
        }
        __syncthreads();

        // gates = h @ Uslice: 2 accumulators halve the dependent-MFMA chain
        f32x16 a0 = {0,0,0,0, 0,0,0,0, 0,0,0,0, 0,0,0,0};
        f32x16 a1 = {0,0,0,0, 0,0,0,0, 0,0,0,0, 0,0,0,0};
        #pragma unroll
        for (int kk = 0; kk < 16; kk++) {
            bf16x8 af0 = *(const bf16x8*)&h_lds[col][kk * 16 + half * 8];
            a0 = __builtin_amdgcn_mfma_f32_32x32x16_bf16(af0, ufrag[kk], a0, 0, 0, 0);
            bf16x8 af1 = *(const bf16x8*)&h_lds[col][(kk + 16) * 16 + half * 8];
            a1 = __builtin_amdgcn_mfma_f32_32x32x16_bf16(af1, ufrag[kk + 16], a1, 0, 0, 0);
        }

        // gate exchange (wave-local LDS; in-wave lgkmcnt ordering, no barrier)
        #pragma unroll
        for (int r = 0; r < 16; r++) {
            int b = (r & 3) + ((r >> 2) << 3) + (half << 2);
            float xwv = bf2f(r < 8 ? (u16)xv0[r] : (u16)xv1[r - 8]);
            gl[wave][b][col] = a0[r] + a1[r] + xwv;
        }

        // cell update: each lane owns 4 (batch,unit) pairs
        u32* hb_out = hbuf + ((size_t)(((size_t)t + 1) & 1) << 14);
        const u32 tg1 = ((u32)(t + 1)) << 16;
        #pragma unroll
        for (int i = 0; i < 4; i++) {
            int p = (i << 6) + lane, b = p >> 3, u = p & 7;
            f32x4 g4 = *(const f32x4*)&gl[wave][b][u << 2];   // i,f,g,o
            float si = fsig(g4[0]), sf = fsig(g4[1]);
            float sg = ftanh(g4[2]), so = fsig(g4[3]);
            float c = sf * cst[i] + si * sg;
            cst[i] = c;
            float h = so * ftanh(c);
            u16 hv = f2bf(h);
            int j = (wg64 << 3) + u;
            hseq[((size_t)b * S_ + t) * NH_ + j] = hv;        // cached; read post-kernel
            u32 pk = tg1 | (u32)hv;
            u32* hp = hb_out + b * 512 + j;
            asm volatile("global_store_dword %0, %1, off sc0 sc1"
                         :: "v"(hp), "v"(pk) : "memory");
        }
        // fire-and-forget: no drain, no flag, no second barrier
    }
}

extern "C" void kernel_launch(void* const* d_in, const int* in_sizes, int n_in,
                              void* d_out, int out_size, void* d_ws, size_t ws_size,
                              hipStream_t stream) {
    const float* x        = (const float*)d_in[0];
    const float* W        = (const float*)d_in[1];
    const float* U        = (const float*)d_in[2];
    const float* hid_bias = (const float*)d_in[3];
    const float* V        = (const float*)d_in[4];
    const float* out_bias = (const float*)d_in[5];

    char* ws = (char*)d_ws;
    size_t off = 0;
    auto carve = [&](size_t bytes) -> void* {
        void* p = ws + off;
        off += (bytes + 255) & ~(size_t)255;
        return p;
    };
    u16* xw    = (u16*)carve((size_t)B_ * S_ * G4_ * 2);   // 128 MB, scan-order
    u16* xbf   = (u16*)carve((size_t)B_ * S_ * NH_ * 2);   //  32 MB
    u16* hseq  = (u16*)carve((size_t)B_ * S_ * NH_ * 2);   //  32 MB
    u16* WT    = (u16*)carve((size_t)G4_ * NH_ * 2);       //   2 MB
    u16* UT    = (u16*)carve((size_t)G4_ * NH_ * 2);       //   2 MB
    u16* VT    = (u16*)carve((size_t)NH_ * NH_ * 2);       // 512 KB
    u32* hbuf  = (u32*)carve((size_t)2 * B_ * NH_ * 4);    // 128 KB tagged h

    int n4 = B_ * S_ * NH_ / 4;
    cvt_bf16_kernel<<<(n4 + 255) / 256, 256, 0, stream>>>(x, xbf, n4);
    transpose_cvt_kernel<<<dim3(G4_ / 32, NH_ / 32), 256, 0, stream>>>(W, WT, NH_, G4_);
    transpose_cvt_kernel<<<dim3(G4_ / 32, NH_ / 32), 256, 0, stream>>>(U, UT, NH_, G4_);
    transpose_cvt_kernel<<<dim3(NH_ / 32, NH_ / 32), 256, 0, stream>>>(V, VT, NH_, NH_);

    // xW + hid_bias -> bf16, stored in scan order
    gemm_bf16_kernel<<<4096, 256, 0, stream>>>(xbf, WT, hid_bias, xw,
                                               B_ * S_, G4_, NH_, 1);
    // sequential LSTM scan
    lstm_scan_kernel<<<SC_NWG, 512, 0, stream>>>(xw, UT, hseq, hbuf);
    // out = hseq @ V + out_bias -> f32
    gemm_bf16_kernel<<<1024, 256, 0, stream>>>(hseq, VT, out_bias, d_out,
                                               B_ * S_, NH_, NH_, 0);
}